// Round 11
// baseline (261.354 us; speedup 1.0000x reference)
//
#include <hip/hip_runtime.h>
#include <cstdint>
#include <cstddef>

#define Bb 4
#define Nn 4096
#define Dd 1024
#define Hh 16
#define ROWS (Bb*Nn)   // 16384

typedef unsigned short u16;
typedef float    f32x4 __attribute__((ext_vector_type(4)));
typedef _Float16 f16x8 __attribute__((ext_vector_type(8)));
typedef u16      u16x4 __attribute__((ext_vector_type(4)));
typedef u16      u16x8 __attribute__((ext_vector_type(8)));

__device__ inline u16 f2h(float f){ _Float16 h=(_Float16)f; return __builtin_bit_cast(u16,h); }
__device__ inline float h2f(u16 u){ return (float)__builtin_bit_cast(_Float16,u); }

__device__ inline void gl_lds16(const void* g, void* l){
  __builtin_amdgcn_global_load_lds(
      (const __attribute__((address_space(1))) void*)g,
      (__attribute__((address_space(3))) void*)l,
      16, 0, 0);
}

// ------- weights fp32->fp16, plus q/k/v bias concat -------
__global__ __launch_bounds__(256) void wconv_k(const float* __restrict__ wq,
    const float* __restrict__ wk, const float* __restrict__ wv,
    const float* __restrict__ wo,
    const float* __restrict__ bq, const float* __restrict__ bk,
    const float* __restrict__ bv,
    u16* __restrict__ wbf, float* __restrict__ bcat)
{
  const int idx = blockIdx.x*256 + threadIdx.x;
  if (idx < (1<<20)){
    const int which = idx >> 18;
    const int rem = idx & ((1<<18)-1);
    const float* src = which==0?wq:which==1?wk:which==2?wv:wo;
    const f32x4 v = ((const f32x4*)src)[rem];
    u16x4 o;
    #pragma unroll
    for (int i=0;i<4;i++) o[i]=f2h(v[i]);
    ((u16x4*)(wbf + (size_t)which*(1u<<20)))[rem] = o;
  } else {
    const int t = idx - (1<<20);
    if (t < 3072)
      bcat[t] = (t<1024) ? bq[t] : (t<2048) ? bk[t-1024] : bv[t-2048];
  }
}

// ------- log map: x -> x_tan (fp16) -------
__global__ __launch_bounds__(256) void logmap_k(const float* __restrict__ x,
    const float* __restrict__ curv, u16* __restrict__ xt)
{
  const int row = blockIdx.x, tid = threadIdx.x;
  const f32x4 v = ((const f32x4*)(x + (size_t)row*Dd))[tid];
  float ss = v[0]*v[0] + v[1]*v[1] + v[2]*v[2] + v[3]*v[3];
  #pragma unroll
  for (int o=32;o>0;o>>=1) ss += __shfl_down(ss, o, 64);
  __shared__ float red[4];
  if ((tid & 63) == 0) red[tid>>6] = ss;
  __syncthreads();
  const float sum = red[0]+red[1]+red[2]+red[3];
  const float c  = fmaxf(fabsf(curv[0]), 1e-6f);
  const float sc = sqrtf(fmaxf(c, 1e-6f));
  const float xn = fminf(fmaxf(sqrtf(sum), 1e-6f), 0.999f);
  const float a  = sc * xn;
  const float scale = atanhf(a) / (a + 1e-8f);
  u16x4 o;
  #pragma unroll
  for (int i=0;i<4;i++) o[i] = f2h(v[i]*scale);
  ((u16x4*)(xt + (size_t)row*Dd))[tid] = o;
}

// ------- exp map: proj (fp16) -> out (fp32) -------
__global__ __launch_bounds__(256) void expmap_k(const u16* __restrict__ proj,
    const float* __restrict__ curv, float* __restrict__ out)
{
  const int row = blockIdx.x, tid = threadIdx.x;
  const u16x4 hv = ((const u16x4*)(proj + (size_t)row*Dd))[tid];
  float v[4];
  #pragma unroll
  for (int i=0;i<4;i++) v[i]=h2f(hv[i]);
  float ss = v[0]*v[0]+v[1]*v[1]+v[2]*v[2]+v[3]*v[3];
  #pragma unroll
  for (int o=32;o>0;o>>=1) ss += __shfl_down(ss,o,64);
  __shared__ float red[4];
  if ((tid&63)==0) red[tid>>6]=ss;
  __syncthreads();
  const float sum = red[0]+red[1]+red[2]+red[3];
  const float c  = fmaxf(fabsf(curv[0]),1e-6f);
  const float sc = sqrtf(fmaxf(c,1e-6f));
  const float vn = fminf(fmaxf(sqrtf(sum),1e-6f),15.0f);
  const float a  = sc*vn;
  const float scale = tanhf(fminf(a,15.0f))/(a + 1e-8f);
  f32x4 o;
  #pragma unroll
  for (int i=0;i<4;i++) o[i]=v[i]*scale;
  ((f32x4*)(out + (size_t)row*Dd))[tid]=o;
}

// ------- 128x128-tile GEMM, 4 waves (2x2), BK=64, dbuf 64KB -> 2 blocks/CU.
// Cross-block wave overlap (m114) hides per-tile barrier/drain dead time.
// mode0: row-major store. modes 1/2 (phik/v): transposed -> [bh][f][n].
__global__ __launch_bounds__(256, 2) void gemm4_k(
    const u16* __restrict__ A, const u16* __restrict__ W,
    const float* __restrict__ bias,
    u16* __restrict__ out_n, u16* __restrict__ outT1, u16* __restrict__ outT2,
    int nbn, int phi_modes)
{
  __shared__ __align__(16) char smem[65536];

  const int nwg = gridDim.x;
  const int bid = blockIdx.x;
  const int wgid = (bid & 7)*(nwg >> 3) + (bid >> 3);   // XCD-chunked (nwg%8==0)
  const int bm = wgid / nbn, bn = wgid % nbn;           // bm-major: A-tile L2 reuse
  const int bm0 = bm*128, bn0 = bn*128;

  const int tid = threadIdx.x;
  const int w = tid >> 6, lane = tid & 63;
  const int wr = w >> 1, wc = w & 1;                    // 2M x 2N wave grid
  const int l8 = lane >> 3, l7 = lane & 7;

  f32x4 acc[4][4];
  #pragma unroll
  for (int i=0;i<4;i++)
    #pragma unroll
    for (int j=0;j<4;j++) acc[i][j] = (f32x4)(0.f);

  auto STAGE = [&](int d, int kt){
    char* Ab = smem + d*32768;
    char* Bbp = Ab + 16384;
    #pragma unroll
    for (int i=0;i<4;i++){
      const int r = w*32 + i*8 + l8;
      const int cch = l7 ^ (r & 7);
      gl_lds16(A + (size_t)(bm0 + r)*Dd + kt*64 + cch*8, Ab + (w*32+i*8)*128);
      gl_lds16(W + (size_t)(bn0 + r)*Dd + kt*64 + cch*8, Bbp + (w*32+i*8)*128);
    }
  };

  auto COMPUTE = [&](int d){
    const char* Ab = smem + d*32768;
    const char* Bbp = Ab + 16384;
    #pragma unroll
    for (int ks=0; ks<2; ks++){
      f16x8 bf[4];
      #pragma unroll
      for (int ni=0; ni<4; ni++){
        const int br = wc*64 + ni*16 + (lane & 15);
        const int cb = (ks*64 + (lane>>4)*16) ^ ((br & 7) << 4);   // T2 swizzle
        bf[ni] = *(const f16x8*)(Bbp + br*128 + cb);
      }
      __builtin_amdgcn_s_setprio(1);
      #pragma unroll
      for (int mi=0; mi<4; mi++){
        const int ar = wr*64 + mi*16 + (lane & 15);
        const int cb = (ks*64 + (lane>>4)*16) ^ ((ar & 7) << 4);
        const f16x8 af = *(const f16x8*)(Ab + ar*128 + cb);
        #pragma unroll
        for (int ni=0; ni<4; ni++)
          acc[mi][ni] = __builtin_amdgcn_mfma_f32_16x16x32_f16(af, bf[ni], acc[mi][ni], 0,0,0);
      }
      __builtin_amdgcn_s_setprio(0);
    }
  };

  STAGE(0, 0);
  __syncthreads();
  int d = 0;
  for (int kt = 0; kt < Dd/64; ++kt){
    if (kt < Dd/64 - 1) STAGE(d^1, kt+1);   // issue-first: latency hides under MFMA
    COMPUTE(d);
    __syncthreads();                         // single drain per K-tile
    d ^= 1;
  }

  const int mode = bn0 >> 10;
  const int dophi = mode < phi_modes;
  if (mode == 1 || mode == 2){
    // ---- transposed epilogue: Ts[col 128][256B rows], then [bh][f][n] stores
    u16* tbuf = (mode == 1) ? outT1 : outT2;
    char* Ts = smem;
    #pragma unroll
    for (int ni=0;ni<4;ni++){
      const int lcol = wc*64 + ni*16 + (lane & 15);
      const float bs = bias[bn0 + lcol];
      #pragma unroll
      for (int mi=0;mi<4;mi++){
        const int row0 = wr*64 + mi*16 + ((lane>>4)<<2);
        #pragma unroll
        for (int r=0;r<4;r++){
          float val = acc[mi][ni][r] + bs;
          if (dophi) val = val > 0.f ? val + 1.f : __expf(val);
          const int lrow = row0 + r;
          const int bo_ = (lcol*256 + lrow*2) ^ ((lcol&7)<<4);
          *(u16*)(Ts + bo_) = f2h(val);
        }
      }
    }
    __syncthreads();
    {
      const int ch = tid & 15;               // 16B chunk within 256B column
      #pragma unroll
      for (int rep=0; rep<8; ++rep){
        const int c = rep*16 + (tid>>4);     // quarter-wave per column
        const int bo_ = (c*256 + ch*16) ^ ((c&7)<<4);
        const int mcol = (bn0 & 1023) + c;
        const int h = mcol >> 6, f = mcol & 63;
        const int bh = ((bm0 >> 12) << 4) + h;
        u16* db = tbuf + ((size_t)(bh*64 + f))*Nn + (bm0 & 4095) + ch*8;
        *(u16x8*)db = *(const u16x8*)(Ts + bo_);
      }
    }
  } else {
    // ---- row-major epilogue: LDS transpose + coalesced stores
    u16* Ts = (u16*)smem;
    #pragma unroll
    for (int ni=0;ni<4;ni++){
      const int col = wc*64 + ni*16 + (lane & 15);
      const float bs = bias[bn0 + col];
      #pragma unroll
      for (int mi=0;mi<4;mi++){
        const int row0 = wr*64 + mi*16 + ((lane>>4)<<2);
        #pragma unroll
        for (int r=0;r<4;r++){
          float val = acc[mi][ni][r] + bs;
          if (dophi) val = val > 0.f ? val + 1.f : __expf(val);
          const int row = row0 + r;
          const int bo_ = (row*256 + col*2) ^ ((row&7)<<4);
          *(u16*)((char*)Ts + bo_) = f2h(val);
        }
      }
    }
    __syncthreads();
    #pragma unroll
    for (int j=0;j<8;j++){
      const int row = j*16 + w*4 + (lane>>4);
      const int ch = lane & 15;
      const int bo_ = (row*256 + ch*16) ^ ((row&7)<<4);
      u16* ob = out_n + (size_t)(bm0 + row)*Dd + (bn0 & 1023) + ch*8;
      *(u16x8*)ob = *(const u16x8*)((const char*)Ts + bo_);
    }
  }
}

// ------- kv GEMM via MFMA: pkv[bh][p] = phikT-strip @ vT-strip^T -------
__global__ __launch_bounds__(256) void kvmm_k(const u16* __restrict__ pkT,
    const u16* __restrict__ vT, float* __restrict__ pkv, float* __restrict__ pks)
{
  const int p = blockIdx.x, bh = blockIdx.y;
  const int tid = threadIdx.x, w = tid>>6, lane = tid&63;
  __shared__ __align__(16) char smem[65536];      // 2 x (Ap 16KB + Bp 16KB)
  const size_t abase = (size_t)bh*64*Nn;

  f32x4 acc[5];
  #pragma unroll
  for (int i=0;i<5;i++) acc[i] = (f32x4)(0.f);
  f16x8 onesf;
  #pragma unroll
  for (int i=0;i<8;i++) onesf[i] = (_Float16)1.0f;

  auto STG = [&](int d, int sub){
    char* Ap = smem + d*32768;
    char* Bp = Ap + 16384;
    const int nbase = p*512 + sub*128;
    #pragma unroll
    for (int i=0;i<4;i++){
      const int ib = (w*4+i)*64;
      const int cj = ib + lane;
      const int f = cj>>4, ci = cj&15;
      const size_t off = abase + (size_t)f*Nn + nbase + (ci ^ (f&15))*8;
      gl_lds16(pkT + off, Ap + ib*16);
      gl_lds16(vT  + off, Bp + ib*16);
    }
  };

  auto COMPUTE = [&](int d){
    const char* Ap = smem + d*32768;
    const char* Bp = Ap + 16384;
    #pragma unroll
    for (int s=0; s<4; ++s){
      const int kb = (s*64 + (lane>>4)*16) ^ ((lane&15)<<4);
      const int fr = w*16 + (lane&15);
      const f16x8 af = *(const f16x8*)(Ap + fr*256 + kb);
      #pragma unroll
      for (int ni=0; ni<4; ni++){
        const int dr = ni*16 + (lane&15);
        const f16x8 bf = *(const f16x8*)(Bp + dr*256 + kb);
        acc[ni] = __builtin_amdgcn_mfma_f32_16x16x32_f16(af, bf, acc[ni], 0,0,0);
      }
      acc[4] = __builtin_amdgcn_mfma_f32_16x16x32_f16(af, onesf, acc[4], 0,0,0);
    }
  };

  STG(0, 0);
  __syncthreads();
  for (int sub=0; sub<4; ++sub){
    const int d = sub & 1;
    if (sub < 3) STG(d^1, sub+1);
    COMPUTE(d);
    __syncthreads();
  }

  float* o = pkv + (size_t)(bh*8+p)*4096;
  #pragma unroll
  for (int ni=0;ni<4;ni++)
    #pragma unroll
    for (int r=0;r<4;r++)
      o[(w*16 + ((lane>>4)<<2) + r)*64 + ni*16 + (lane&15)] = acc[ni][r];
  if ((lane&15)==0){
    #pragma unroll
    for (int r=0;r<4;r++)
      pks[(size_t)(bh*8+p)*64 + w*16 + ((lane>>4)<<2) + r] = acc[4][r];
  }
}

// ------- reduce partials; emit transposed, pre-swizzled, hi/lo fp16 kvt -------
__global__ __launch_bounds__(256) void kvred_k(const float* __restrict__ pkv,
    const float* __restrict__ pks, u16* __restrict__ kvt)
{
  const int bh = blockIdx.x, tid = threadIdx.x;
  u16* basep = kvt + (size_t)bh*10240;
  #pragma unroll
  for (int i=0;i<4;i++){
    const int e = tid*16 + i*4;
    f32x4 s = (f32x4)(0.f);
    for (int p=0;p<8;p++)
      s += *(const f32x4*)&pkv[(size_t)(bh*8+p)*4096 + e];
    const int f = e>>6, dd = e&63;
    #pragma unroll
    for (int j=0;j<4;j++){
      const int r = dd+j;
      const u16 hi = f2h(s[j]);
      const int col = f ^ ((r&7)<<3);
      basep[r*64 + col] = hi;
      basep[5120 + r*64 + col] = f2h(s[j] - h2f(hi));
    }
  }
  if (tid < 64){
    float s=0.f;
    for (int p=0;p<8;p++) s += pks[(size_t)(bh*8+p)*64 + tid];
    const u16 hi = f2h(s);
    basep[64*64 + tid] = hi;                       // (64&7)==0: no swizzle
    basep[5120 + 64*64 + tid] = f2h(s - h2f(hi));
  }
  if (tid < 240){                                  // zero rows 65..79
    const int r = 65 + (tid>>4), c4 = (tid&15)*4;
    *(u16x4*)&basep[r*64 + c4] = (u16x4)(0);
    *(u16x4*)&basep[5120 + r*64 + c4] = (u16x4)(0);
  }
}

// ------- attention core via MFMA: out = (phiq @ kv) / (phiq @ ksum) -------
__global__ __launch_bounds__(256) void attn2_k(const u16* __restrict__ phiq,
    const u16* __restrict__ kvt, u16* __restrict__ att)
{
  const int bh = blockIdx.y, b = bh>>4, h = bh&15;
  const int tid = threadIdx.x;
  const int w = tid>>6, lane = tid&63;
  __shared__ __align__(16) u16 kvs[10240];      // [2][80][64], pre-swizzled rows
  __shared__ __align__(16) u16 pqs[2][64*64];   // double-buffered Q tiles

  const int l8 = lane>>3, l7 = lane&7;
  auto STAGE_P = [&](int d, int nt){
    const int n0 = (blockIdx.x*4 + nt)*64;
    const u16* qsrc = phiq + ((size_t)(b*Nn) + n0)*Dd + h*64;
    #pragma unroll
    for (int i=0;i<2;i++){
      const int r = w*16 + i*8 + l8;
      const int cch = l7 ^ (r&7);
      gl_lds16(qsrc + (size_t)r*Dd + cch*8, (char*)pqs[d] + (w*16+i*8)*128);
    }
  };

  {
    const char* src = (const char*)(kvt + (size_t)bh*10240);
    #pragma unroll
    for (int j=0;j<5;j++)
      gl_lds16(src + j*4096 + w*1024 + lane*16, (char*)kvs + j*4096 + w*1024);
    STAGE_P(0, 0);
  }
  __syncthreads();

  #pragma unroll
  for (int nt=0; nt<4; ++nt){
    const int d = nt & 1;
    if (nt < 3) STAGE_P(d^1, nt+1);     // issue-first; barrier at loop end syncs
    f32x4 acc[5];
    #pragma unroll
    for (int ni=0;ni<5;ni++) acc[ni] = (f32x4)(0.f);
    #pragma unroll
    for (int ks=0; ks<2; ks++){
      const int ar = w*16 + (lane&15);
      const int acb = (ks*64 + (lane>>4)*16) ^ ((ar&7)<<4);
      const f16x8 af = *(const f16x8*)((const char*)pqs[d] + ar*128 + acb);
      #pragma unroll
      for (int ni=0; ni<5; ni++){
        const int br = ni*16 + (lane&15);
        const int bcb = (ks*64 + (lane>>4)*16) ^ ((br&7)<<4);
        const f16x8 bh_ = *(const f16x8*)((const char*)kvs + br*128 + bcb);
        const f16x8 bl_ = *(const f16x8*)((const char*)kvs + 10240 + br*128 + bcb);
        acc[ni] = __builtin_amdgcn_mfma_f32_16x16x32_f16(af, bh_, acc[ni], 0,0,0);
        acc[ni] = __builtin_amdgcn_mfma_f32_16x16x32_f16(af, bl_, acc[ni], 0,0,0);
      }
    }
    const int n0 = (blockIdx.x*4 + nt)*64;
    #pragma unroll
    for (int r=0;r<4;r++){
      const float nrm = __shfl(acc[4][r], (lane & 48), 64);   // col 64 of C
      const float inv = 1.f / fmaxf(nrm, 1e-6f);
      const int row = n0 + w*16 + ((lane>>4)<<2) + r;
      u16* ob = att + ((size_t)(b*Nn) + row)*Dd + h*64 + (lane&15);
      #pragma unroll
      for (int ni=0; ni<4; ni++)
        ob[ni*16] = f2h(acc[ni][r] * inv);
    }
    __syncthreads();                    // staged pqs landed; prev buffer free
  }
}

extern "C" void kernel_launch(void* const* d_in, const int* in_sizes, int n_in,
                              void* d_out, int out_size, void* d_ws, size_t ws_size,
                              hipStream_t stream)
{
  const float* x  = (const float*)d_in[0];
  const float* cv = (const float*)d_in[1];
  const float* Wq = (const float*)d_in[2];
  const float* bq = (const float*)d_in[3];
  const float* Wk = (const float*)d_in[4];
  const float* bk = (const float*)d_in[5];
  const float* Wv = (const float*)d_in[6];
  const float* bv = (const float*)d_in[7];
  const float* Wo = (const float*)d_in[8];
  const float* bo = (const float*)d_in[9];
  float* out = (float*)d_out;
  char* ws = (char*)d_ws;
  const size_t MB = 1u<<20;
  if (ws_size < 136*MB) return;

  u16* xt     = (u16*)(ws + 0);        // 32 MiB, dead after QKV gemm
  u16* wbf    = (u16*)(ws + 32*MB);    // 8 MiB (Wq|Wk|Wv|Wo fp16)
  u16* phiq   = (u16*)(ws + 40*MB);    // 32 MiB row-major [b,n][h,f]
  u16* phikT  = (u16*)(ws + 72*MB);    // 32 MiB transposed [bh][f][n]
  u16* vT     = (u16*)(ws + 104*MB);   // 32 MiB transposed [bh][d][n]
  float* pkv  = (float*)(ws + 0);      // 8 MiB, reuses xt after QKV gemm
  float* pks  = (float*)(ws + 8*MB);   // 128 KiB
  u16* kvt    = (u16*)(ws + 9*MB);     // 1.25 MiB [64][2][80][64] u16
  u16* att    = (u16*)(ws + 104*MB);   // reuses vT after kvmm
  u16* proj16 = (u16*)(ws + 40*MB);    // reuses phiq after attn2
  float* bcat = out + ((size_t)out_size - 4096);  // d_out tail, dead before expmap

  wconv_k<<<4108, 256, 0, stream>>>(Wq, Wk, Wv, Wo, bq, bk, bv, wbf, bcat);
  logmap_k<<<ROWS, 256, 0, stream>>>(x, cv, xt);
  gemm4_k<<<3072, 256, 0, stream>>>(xt, wbf, bcat, phiq, phikT, vT,
                                    24, 2);                      // fused QKV
  kvmm_k<<<dim3(8,64), 256, 0, stream>>>(phikT, vT, pkv, pks);
  kvred_k<<<64, 256, 0, stream>>>(pkv, pks, kvt);
  attn2_k<<<dim3(16,64), 256, 0, stream>>>(phiq, kvt, att);
  gemm4_k<<<1024, 256, 0, stream>>>(att, wbf + (size_t)3*(1u<<20), bo, proj16,
                                    nullptr, nullptr, 8, 0);     // out-proj
  expmap_k<<<ROWS, 256, 0, stream>>>(proj16, cv, out);
}

// Round 12
// 233.054 us; speedup vs baseline: 1.1214x; 1.1214x over previous
//
#include <hip/hip_runtime.h>
#include <cstdint>
#include <cstddef>

#define Bb 4
#define Nn 4096
#define Dd 1024
#define Hh 16
#define ROWS (Bb*Nn)   // 16384

typedef unsigned short u16;
typedef float    f32x4 __attribute__((ext_vector_type(4)));
typedef _Float16 f16x8 __attribute__((ext_vector_type(8)));
typedef u16      u16x4 __attribute__((ext_vector_type(4)));
typedef u16      u16x8 __attribute__((ext_vector_type(8)));

__device__ inline u16 f2h(float f){ _Float16 h=(_Float16)f; return __builtin_bit_cast(u16,h); }
__device__ inline float h2f(u16 u){ return (float)__builtin_bit_cast(_Float16,u); }

__device__ inline void gl_lds16(const void* g, void* l){
  __builtin_amdgcn_global_load_lds(
      (const __attribute__((address_space(1))) void*)g,
      (__attribute__((address_space(3))) void*)l,
      16, 0, 0);
}

// ------- merged prep: logmap (blocks 0..16383) + weight conv (rest) -------
__global__ __launch_bounds__(256) void prep_k(const float* __restrict__ x,
    const float* __restrict__ curv,
    const float* __restrict__ wq, const float* __restrict__ wk,
    const float* __restrict__ wv, const float* __restrict__ wo,
    const float* __restrict__ bq, const float* __restrict__ bk,
    const float* __restrict__ bv,
    u16* __restrict__ xt, u16* __restrict__ wbf, float* __restrict__ bcat)
{
  const int tid = threadIdx.x;
  if (blockIdx.x < ROWS){
    const int row = blockIdx.x;
    const f32x4 v = ((const f32x4*)(x + (size_t)row*Dd))[tid];
    float ss = v[0]*v[0] + v[1]*v[1] + v[2]*v[2] + v[3]*v[3];
    #pragma unroll
    for (int o=32;o>0;o>>=1) ss += __shfl_down(ss, o, 64);
    __shared__ float red[4];
    if ((tid & 63) == 0) red[tid>>6] = ss;
    __syncthreads();
    const float sum = red[0]+red[1]+red[2]+red[3];
    const float c  = fmaxf(fabsf(curv[0]), 1e-6f);
    const float sc = sqrtf(fmaxf(c, 1e-6f));
    const float xn = fminf(fmaxf(sqrtf(sum), 1e-6f), 0.999f);
    const float a  = sc * xn;
    const float scale = atanhf(a) / (a + 1e-8f);
    u16x4 o;
    #pragma unroll
    for (int i=0;i<4;i++) o[i] = f2h(v[i]*scale);
    ((u16x4*)(xt + (size_t)row*Dd))[tid] = o;
  } else {
    const int idx = (blockIdx.x - ROWS)*256 + tid;
    if (idx < (1<<20)){
      const int which = idx >> 18;
      const int rem = idx & ((1<<18)-1);
      const float* src = which==0?wq:which==1?wk:which==2?wv:wo;
      const f32x4 v = ((const f32x4*)src)[rem];
      u16x4 o;
      #pragma unroll
      for (int i=0;i<4;i++) o[i]=f2h(v[i]);
      ((u16x4*)(wbf + (size_t)which*(1u<<20)))[rem] = o;
    } else {
      const int t = idx - (1<<20);
      if (t < 3072)
        bcat[t] = (t<1024) ? bq[t] : (t<2048) ? bk[t-1024] : bv[t-2048];
    }
  }
}

// ------- exp map: proj (fp16) -> out (fp32) -------
__global__ __launch_bounds__(256) void expmap_k(const u16* __restrict__ proj,
    const float* __restrict__ curv, float* __restrict__ out)
{
  const int row = blockIdx.x, tid = threadIdx.x;
  const u16x4 hv = ((const u16x4*)(proj + (size_t)row*Dd))[tid];
  float v[4];
  #pragma unroll
  for (int i=0;i<4;i++) v[i]=h2f(hv[i]);
  float ss = v[0]*v[0]+v[1]*v[1]+v[2]*v[2]+v[3]*v[3];
  #pragma unroll
  for (int o=32;o>0;o>>=1) ss += __shfl_down(ss,o,64);
  __shared__ float red[4];
  if ((tid&63)==0) red[tid>>6]=ss;
  __syncthreads();
  const float sum = red[0]+red[1]+red[2]+red[3];
  const float c  = fmaxf(fabsf(curv[0]),1e-6f);
  const float sc = sqrtf(fmaxf(c,1e-6f));
  const float vn = fminf(fmaxf(sqrtf(sum),1e-6f),15.0f);
  const float a  = sc*vn;
  const float scale = tanhf(fminf(a,15.0f))/(a + 1e-8f);
  f32x4 o;
  #pragma unroll
  for (int i=0;i<4;i++) o[i]=v[i]*scale;
  ((f32x4*)(out + (size_t)row*Dd))[tid]=o;
}

// ------- 256x256-tile GEMM, fully-unrolled K-loop, hoisted addresses -------
// 8 waves (2Mx4N), BK=64, 2x64KB dbuf, issue-first prefetch.
// All LDS read offsets + global stage pointers precomputed outside the loop;
// per-tile kt*128B folds into load offset immediates (full unroll).
// mode0: row-major store. modes 1/2 (phik/v): transposed -> [bh][f][n].
__global__ __launch_bounds__(512, 1) void gemm8_k(
    const u16* __restrict__ A, const u16* __restrict__ W,
    const float* __restrict__ bias,
    u16* __restrict__ out_n, u16* __restrict__ outT1, u16* __restrict__ outT2,
    int nbn, int phi_modes)
{
  __shared__ __align__(16) char smem[131072];

  const int nwg = gridDim.x;
  const int bid = blockIdx.x;
  const int wgid = (bid & 7)*(nwg >> 3) + (bid >> 3);   // XCD-chunked (nwg%8==0)
  const int bm = wgid / nbn, bn = wgid % nbn;           // bm-major: A-tile L2 reuse
  const int bm0 = bm*256, bn0 = bn*256;

  const int tid = threadIdx.x;
  const int w = tid >> 6, lane = tid & 63;
  const int wr = w >> 2, wc = w & 3;                    // 2M x 4N wave grid
  const int l8 = lane >> 3, l7 = lane & 7;

  f32x4 acc[8][4];
  #pragma unroll
  for (int i=0;i<8;i++)
    #pragma unroll
    for (int j=0;j<4;j++) acc[i][j] = (f32x4)(0.f);

  // ---- hoisted addressing (loop-invariant; statically indexed under unroll)
  int offA[2][8], offB[2][4];
  #pragma unroll
  for (int ks=0;ks<2;ks++){
    #pragma unroll
    for (int mi=0;mi<8;mi++){
      const int ar = wr*128 + mi*16 + (lane & 15);
      offA[ks][mi] = ar*128 + ((ks*64 + (lane>>4)*16) ^ ((ar & 7) << 4));
    }
    #pragma unroll
    for (int ni=0;ni<4;ni++){
      const int br = wc*64 + ni*16 + (lane & 15);
      offB[ks][ni] = 32768 + br*128 + ((ks*64 + (lane>>4)*16) ^ ((br & 7) << 4));
    }
  }
  const u16* aS[4]; const u16* wS[4]; int dOf[4];
  #pragma unroll
  for (int i=0;i<4;i++){
    const int r = w*32 + i*8 + l8;
    const int cch = l7 ^ (r & 7);
    aS[i] = A + (size_t)(bm0 + r)*Dd + cch*8;
    wS[i] = W + (size_t)(bn0 + r)*Dd + cch*8;
    dOf[i] = (w*32 + i*8)*128;
  }

  auto STAGE = [&](char* base, int kt){
    #pragma unroll
    for (int i=0;i<4;i++){
      gl_lds16(aS[i] + kt*64, base + dOf[i]);
      gl_lds16(wS[i] + kt*64, base + 32768 + dOf[i]);
    }
  };

  auto COMPUTE = [&](const char* base){
    #pragma unroll
    for (int ks=0; ks<2; ks++){
      f16x8 bf[4];
      #pragma unroll
      for (int ni=0; ni<4; ni++)
        bf[ni] = *(const f16x8*)(base + offB[ks][ni]);
      __builtin_amdgcn_s_setprio(1);
      #pragma unroll
      for (int mi=0; mi<8; mi++){
        const f16x8 af = *(const f16x8*)(base + offA[ks][mi]);
        #pragma unroll
        for (int ni=0; ni<4; ni++)
          acc[mi][ni] = __builtin_amdgcn_mfma_f32_16x16x32_f16(af, bf[ni], acc[mi][ni], 0,0,0);
      }
      __builtin_amdgcn_s_setprio(0);
    }
  };

  STAGE(smem, 0);
  __syncthreads();
  #pragma unroll
  for (int p=0; p<8; ++p){
    STAGE(smem + 65536, 2*p+1);       // issue-first: latency hides under MFMA
    COMPUTE(smem);
    __syncthreads();
    if (p < 7) STAGE(smem, 2*p+2);
    COMPUTE(smem + 65536);
    __syncthreads();
  }

  const int mode = bn0 >> 10;
  const int dophi = mode < phi_modes;
  if (mode == 1 || mode == 2){
    // ---- transposed epilogue: Ts[col 256][512B rows], then [bh][f][n] stores
    u16* tbuf = (mode == 1) ? outT1 : outT2;
    char* Ts = smem;
    #pragma unroll
    for (int ni=0;ni<4;ni++){
      const int lcol = wc*64 + ni*16 + (lane & 15);
      const float bs = bias[bn0 + lcol];
      #pragma unroll
      for (int mi=0;mi<8;mi++){
        const int row0 = wr*128 + mi*16 + ((lane>>4)<<2);
        #pragma unroll
        for (int r=0;r<4;r++){
          float val = acc[mi][ni][r] + bs;
          if (dophi) val = val > 0.f ? val + 1.f : __expf(val);
          const int lrow = row0 + r;
          const int bo_ = (lcol*512 + lrow*2) ^ ((lcol&7)<<4);
          *(u16*)(Ts + bo_) = f2h(val);
        }
      }
    }
    __syncthreads();
    {
      const int ch = tid & 31;               // 16B chunk within 512B row
      #pragma unroll
      for (int rep=0; rep<16; ++rep){
        const int c = rep*16 + (tid>>5);     // half-wave per column
        const int bo_ = (c*512 + ch*16) ^ ((c&7)<<4);
        const int mcol = (bn0 & 1023) + c;
        const int h = mcol >> 6, f = mcol & 63;
        const int bh = ((bm0 >> 12) << 4) + h;
        u16* db = tbuf + ((size_t)(bh*64 + f))*Nn + (bm0 & 4095) + ch*8;
        *(u16x8*)db = *(const u16x8*)(Ts + bo_);
      }
    }
  } else {
    // ---- row-major epilogue: LDS transpose + coalesced stores
    u16* Ts = (u16*)smem;
    #pragma unroll
    for (int ni=0;ni<4;ni++){
      const int col = wc*64 + ni*16 + (lane & 15);
      const float bs = bias[bn0 + col];
      #pragma unroll
      for (int mi=0;mi<8;mi++){
        const int row0 = wr*128 + mi*16 + ((lane>>4)<<2);
        #pragma unroll
        for (int r=0;r<4;r++){
          float val = acc[mi][ni][r] + bs;
          if (dophi) val = val > 0.f ? val + 1.f : __expf(val);
          const int row = row0 + r;
          const int bo_ = (row*512 + col*2) ^ ((row&7)<<4);
          *(u16*)((char*)Ts + bo_) = f2h(val);
        }
      }
    }
    __syncthreads();
    #pragma unroll
    for (int j=0;j<16;j++){
      const int row = j*16 + w*2 + (lane>>5);
      const int cb2 = (lane&31)*16;
      const int bo_ = (row*512 + cb2) ^ ((row&7)<<4);
      u16* ob = out_n + (size_t)(bm0 + row)*Dd + (bn0 & 1023) + (cb2>>1);
      *(u16x8*)ob = *(const u16x8*)((const char*)Ts + bo_);
    }
  }
}

// ------- kv GEMM via MFMA: pkv[bh][p] = phikT-strip @ vT-strip^T -------
__global__ __launch_bounds__(256) void kvmm_k(const u16* __restrict__ pkT,
    const u16* __restrict__ vT, float* __restrict__ pkv, float* __restrict__ pks)
{
  const int p = blockIdx.x, bh = blockIdx.y;
  const int tid = threadIdx.x, w = tid>>6, lane = tid&63;
  __shared__ __align__(16) char smem[65536];      // 2 x (Ap 16KB + Bp 16KB)
  const size_t abase = (size_t)bh*64*Nn;

  f32x4 acc[5];
  #pragma unroll
  for (int i=0;i<5;i++) acc[i] = (f32x4)(0.f);
  f16x8 onesf;
  #pragma unroll
  for (int i=0;i<8;i++) onesf[i] = (_Float16)1.0f;

  auto STG = [&](int d, int sub){
    char* Ap = smem + d*32768;
    char* Bp = Ap + 16384;
    const int nbase = p*512 + sub*128;
    #pragma unroll
    for (int i=0;i<4;i++){
      const int ib = (w*4+i)*64;
      const int cj = ib + lane;
      const int f = cj>>4, ci = cj&15;
      const size_t off = abase + (size_t)f*Nn + nbase + (ci ^ (f&15))*8;
      gl_lds16(pkT + off, Ap + ib*16);
      gl_lds16(vT  + off, Bp + ib*16);
    }
  };

  auto COMPUTE = [&](int d){
    const char* Ap = smem + d*32768;
    const char* Bp = Ap + 16384;
    #pragma unroll
    for (int s=0; s<4; ++s){
      const int kb = (s*64 + (lane>>4)*16) ^ ((lane&15)<<4);
      const int fr = w*16 + (lane&15);
      const f16x8 af = *(const f16x8*)(Ap + fr*256 + kb);
      #pragma unroll
      for (int ni=0; ni<4; ni++){
        const int dr = ni*16 + (lane&15);
        const f16x8 bf = *(const f16x8*)(Bp + dr*256 + kb);
        acc[ni] = __builtin_amdgcn_mfma_f32_16x16x32_f16(af, bf, acc[ni], 0,0,0);
      }
      acc[4] = __builtin_amdgcn_mfma_f32_16x16x32_f16(af, onesf, acc[4], 0,0,0);
    }
  };

  STG(0, 0);
  __syncthreads();
  for (int sub=0; sub<4; ++sub){
    const int d = sub & 1;
    if (sub < 3) STG(d^1, sub+1);
    COMPUTE(d);
    __syncthreads();
  }

  float* o = pkv + (size_t)(bh*8+p)*4096;
  #pragma unroll
  for (int ni=0;ni<4;ni++)
    #pragma unroll
    for (int r=0;r<4;r++)
      o[(w*16 + ((lane>>4)<<2) + r)*64 + ni*16 + (lane&15)] = acc[ni][r];
  if ((lane&15)==0){
    #pragma unroll
    for (int r=0;r<4;r++)
      pks[(size_t)(bh*8+p)*64 + w*16 + ((lane>>4)<<2) + r] = acc[4][r];
  }
}

// ------- reduce partials; emit transposed, pre-swizzled, hi/lo fp16 kvt -------
__global__ __launch_bounds__(256) void kvred_k(const float* __restrict__ pkv,
    const float* __restrict__ pks, u16* __restrict__ kvt)
{
  const int bh = blockIdx.x, tid = threadIdx.x;
  u16* basep = kvt + (size_t)bh*10240;
  #pragma unroll
  for (int i=0;i<4;i++){
    const int e = tid*16 + i*4;
    f32x4 s = (f32x4)(0.f);
    for (int p=0;p<8;p++)
      s += *(const f32x4*)&pkv[(size_t)(bh*8+p)*4096 + e];
    const int f = e>>6, dd = e&63;
    #pragma unroll
    for (int j=0;j<4;j++){
      const int r = dd+j;
      const u16 hi = f2h(s[j]);
      const int col = f ^ ((r&7)<<3);
      basep[r*64 + col] = hi;
      basep[5120 + r*64 + col] = f2h(s[j] - h2f(hi));
    }
  }
  if (tid < 64){
    float s=0.f;
    for (int p=0;p<8;p++) s += pks[(size_t)(bh*8+p)*64 + tid];
    const u16 hi = f2h(s);
    basep[64*64 + tid] = hi;                       // (64&7)==0: no swizzle
    basep[5120 + 64*64 + tid] = f2h(s - h2f(hi));
  }
  if (tid < 240){                                  // zero rows 65..79
    const int r = 65 + (tid>>4), c4 = (tid&15)*4;
    *(u16x4*)&basep[r*64 + c4] = (u16x4)(0);
    *(u16x4*)&basep[5120 + r*64 + c4] = (u16x4)(0);
  }
}

// ------- attention core via MFMA: out = (phiq @ kv) / (phiq @ ksum) -------
__global__ __launch_bounds__(256) void attn2_k(const u16* __restrict__ phiq,
    const u16* __restrict__ kvt, u16* __restrict__ att)
{
  const int bh = blockIdx.y, b = bh>>4, h = bh&15;
  const int tid = threadIdx.x;
  const int w = tid>>6, lane = tid&63;
  __shared__ __align__(16) u16 kvs[10240];      // [2][80][64], pre-swizzled rows
  __shared__ __align__(16) u16 pqs[2][64*64];   // double-buffered Q tiles

  const int l8 = lane>>3, l7 = lane&7;
  auto STAGE_P = [&](int d, int nt){
    const int n0 = (blockIdx.x*4 + nt)*64;
    const u16* qsrc = phiq + ((size_t)(b*Nn) + n0)*Dd + h*64;
    #pragma unroll
    for (int i=0;i<2;i++){
      const int r = w*16 + i*8 + l8;
      const int cch = l7 ^ (r&7);
      gl_lds16(qsrc + (size_t)r*Dd + cch*8, (char*)pqs[d] + (w*16+i*8)*128);
    }
  };

  {
    const char* src = (const char*)(kvt + (size_t)bh*10240);
    #pragma unroll
    for (int j=0;j<5;j++)
      gl_lds16(src + j*4096 + w*1024 + lane*16, (char*)kvs + j*4096 + w*1024);
    STAGE_P(0, 0);
  }
  __syncthreads();

  #pragma unroll
  for (int nt=0; nt<4; ++nt){
    const int d = nt & 1;
    if (nt < 3) STAGE_P(d^1, nt+1);     // issue-first; barrier at loop end syncs
    f32x4 acc[5];
    #pragma unroll
    for (int ni=0;ni<5;ni++) acc[ni] = (f32x4)(0.f);
    #pragma unroll
    for (int ks=0; ks<2; ks++){
      const int ar = w*16 + (lane&15);
      const int acb = (ks*64 + (lane>>4)*16) ^ ((ar&7)<<4);
      const f16x8 af = *(const f16x8*)((const char*)pqs[d] + ar*128 + acb);
      #pragma unroll
      for (int ni=0; ni<5; ni++){
        const int br = ni*16 + (lane&15);
        const int bcb = (ks*64 + (lane>>4)*16) ^ ((br&7)<<4);
        const f16x8 bh_ = *(const f16x8*)((const char*)kvs + br*128 + bcb);
        const f16x8 bl_ = *(const f16x8*)((const char*)kvs + 10240 + br*128 + bcb);
        acc[ni] = __builtin_amdgcn_mfma_f32_16x16x32_f16(af, bh_, acc[ni], 0,0,0);
        acc[ni] = __builtin_amdgcn_mfma_f32_16x16x32_f16(af, bl_, acc[ni], 0,0,0);
      }
    }
    const int n0 = (blockIdx.x*4 + nt)*64;
    #pragma unroll
    for (int r=0;r<4;r++){
      const float nrm = __shfl(acc[4][r], (lane & 48), 64);   // col 64 of C
      const float inv = 1.f / fmaxf(nrm, 1e-6f);
      const int row = n0 + w*16 + ((lane>>4)<<2) + r;
      u16* ob = att + ((size_t)(b*Nn) + row)*Dd + h*64 + (lane&15);
      #pragma unroll
      for (int ni=0; ni<4; ni++)
        ob[ni*16] = f2h(acc[ni][r] * inv);
    }
    __syncthreads();                    // staged pqs landed; prev buffer free
  }
}

extern "C" void kernel_launch(void* const* d_in, const int* in_sizes, int n_in,
                              void* d_out, int out_size, void* d_ws, size_t ws_size,
                              hipStream_t stream)
{
  const float* x  = (const float*)d_in[0];
  const float* cv = (const float*)d_in[1];
  const float* Wq = (const float*)d_in[2];
  const float* bq = (const float*)d_in[3];
  const float* Wk = (const float*)d_in[4];
  const float* bk = (const float*)d_in[5];
  const float* Wv = (const float*)d_in[6];
  const float* bv = (const float*)d_in[7];
  const float* Wo = (const float*)d_in[8];
  const float* bo = (const float*)d_in[9];
  float* out = (float*)d_out;
  char* ws = (char*)d_ws;
  const size_t MB = 1u<<20;
  if (ws_size < 136*MB) return;

  u16* xt     = (u16*)(ws + 0);        // 32 MiB, dead after QKV gemm
  u16* wbf    = (u16*)(ws + 32*MB);    // 8 MiB (Wq|Wk|Wv|Wo fp16)
  u16* phiq   = (u16*)(ws + 40*MB);    // 32 MiB row-major [b,n][h,f]
  u16* phikT  = (u16*)(ws + 72*MB);    // 32 MiB transposed [bh][f][n]
  u16* vT     = (u16*)(ws + 104*MB);   // 32 MiB transposed [bh][d][n]
  float* pkv  = (float*)(ws + 0);      // 8 MiB, reuses xt after QKV gemm
  float* pks  = (float*)(ws + 8*MB);   // 128 KiB
  u16* kvt    = (u16*)(ws + 9*MB);     // 1.25 MiB [64][2][80][64] u16
  u16* att    = (u16*)(ws + 104*MB);   // reuses vT after kvmm
  u16* proj16 = (u16*)(ws + 40*MB);    // reuses phiq after attn2
  float* bcat = out + ((size_t)out_size - 4096);  // d_out tail, dead before expmap

  prep_k<<<ROWS + 4108, 256, 0, stream>>>(x, cv, Wq, Wk, Wv, Wo, bq, bk, bv,
                                          xt, wbf, bcat);
  gemm8_k<<<768, 512, 0, stream>>>(xt, wbf, bcat, phiq, phikT, vT,
                                   12, 2);                       // fused QKV
  kvmm_k<<<dim3(8,64), 256, 0, stream>>>(phikT, vT, pkv, pks);
  kvred_k<<<64, 256, 0, stream>>>(pkv, pks, kvt);
  attn2_k<<<dim3(16,64), 256, 0, stream>>>(phiq, kvt, att);
  gemm8_k<<<256, 512, 0, stream>>>(att, wbf + (size_t)3*(1u<<20), bo, proj16,
                                   nullptr, nullptr, 4, 0);      // out-proj
  expmap_k<<<ROWS, 256, 0, stream>>>(proj16, cv, out);
}